// Round 5
// baseline (475.530 us; speedup 1.0000x reference)
//
#include <hip/hip_runtime.h>
#include <stdint.h>

// PressureLSTM: B=4096, T=512, F=32, H=32, gates=128 (i,f,g,o).
// Swapped-MFMA with permuted gate index pg = e*4 + gtype:
//   G^T[pg][b] = sum_k W'[pg][k] * X[b][k]
//   via mfma_f32_16x16x32_bf16(A=W', B=X^T)   <-- A FIRST, B SECOND
// D layout (col=lane&15,row=(lane>>4)*4+reg) => lane's 4 acc regs = i,f,g,o of
// (element e=4*wv+q, batch row b=col): LSTM cell update is fully lane-local.
// One LDS round-trip + ONE barrier per step (h hi/lo, double-buffered).
// 8 batch rows per block (cols 8..15 are harmless duplicates of the neighbor
// block's rows) -> 512 blocks -> 2 independent blocks/CU for phase overlap.
// Depth-2 x prefetch. bf16x3 split (Whi*xhi + Wlo*xhi + Whi*xlo) ~ fp32.

typedef __attribute__((ext_vector_type(8))) short short8;
typedef __attribute__((ext_vector_type(4))) float float4v;

#define T_LEN 512
#define B_ALL 4096
#define ROWS 8
#define NBLK (B_ALL / ROWS)   // 512 blocks
#define HPITCH 40             // shorts per h row (80 B)

static __device__ __forceinline__ void split_bf(float v, short* hi, short* lo) {
    // hi = truncated-bf16(v) (exact masked f32), lo = trunc-bf16(v - hi).
    uint32_t u = __float_as_uint(v);
    uint32_t uh = u & 0xFFFF0000u;
    float lof = v - __uint_as_float(uh);
    *hi = (short)(uh >> 16);
    *lo = (short)(__float_as_uint(lof) >> 16);
}
static __device__ __forceinline__ float bf2f(short s) {
    return __uint_as_float(((uint32_t)(uint16_t)s) << 16);
}
static __device__ __forceinline__ float sigf(float x) {
    float e = __builtin_amdgcn_exp2f(x * -1.44269504f);
    return __builtin_amdgcn_rcpf(1.0f + e);
}
static __device__ __forceinline__ float tanh_fast(float x) {
    float e = __builtin_amdgcn_exp2f(x * 2.88539008f);
    return 1.0f - 2.0f * __builtin_amdgcn_rcpf(1.0f + e);
}
static __device__ __forceinline__ void conv8(float4v a, float4v b, short8* hi, short8* lo) {
    #pragma unroll
    for (int i = 0; i < 8; ++i) {
        float v = (i < 4) ? a[i] : b[i - 4];
        short h_, l_;
        split_bf(v, &h_, &l_);
        (*hi)[i] = h_; (*lo)[i] = l_;
    }
}

__global__ __launch_bounds__(512, 4) void lstm_fused_kernel(
    const float* __restrict__ x,     // [B, T, 32]
    const float* __restrict__ W_ih,  // [128, 32]
    const float* __restrict__ W_hh,  // [128, 32]
    const float* __restrict__ b_ih,  // [128]
    const float* __restrict__ b_hh,  // [128]
    const float* __restrict__ W_fc,  // [1, 32]
    const float* __restrict__ b_fc,  // [1]
    float* __restrict__ out)         // [B]
{
    const int tid  = threadIdx.x;    // 0..511
    const int wv   = tid >> 6;       // wave 0..7 -> elements 4wv..4wv+3
    const int lane = tid & 63;
    const int col  = lane & 15;      // batch row within tile (0..7 real)
    const int q    = lane >> 4;      // 0..3
    const int k0   = q * 8;
    const int b0   = blockIdx.x * ROWS;
    const int e    = 4 * wv + q;     // this lane's h element (0..31)

    __shared__ __align__(16) short lds_hi[2][16][HPITCH];
    __shared__ __align__(16) short lds_lo[2][16][HPITCH];

    // ---- A-fragment weights: lane holds W'[pg = 16wv+col][k0..k0+7]
    // pg = e'*4 + gt with e' = 4wv + (col>>2), gt = col&3 ; memory row = gt*32+e'
    short8 wih_hi, wih_lo, whh_hi, whh_lo;
    {
        const int gmem = (col & 3) * 32 + (4 * wv + (col >> 2));
        const float* wr = W_ih + gmem * 32 + k0;
        const float* hr = W_hh + gmem * 32 + k0;
        #pragma unroll
        for (int i = 0; i < 8; ++i) {
            short h_, l_;
            split_bf(wr[i], &h_, &l_);
            wih_hi[i] = h_; wih_lo[i] = l_;
            split_bf(hr[i], &h_, &l_);
            whh_hi[i] = h_; whh_lo[i] = l_;
        }
    }
    // bias for acc reg r: gate type r of element e (C-init, row-wise constant)
    float4v bias4;
    #pragma unroll
    for (int r = 0; r < 4; ++r) bias4[r] = b_ih[r * 32 + e] + b_hh[r * 32 + e];

    float c = 0.f;
    short8 ah_hi = {0,0,0,0,0,0,0,0};
    short8 ah_lo = {0,0,0,0,0,0,0,0};

    // x source row (cols 8..15 read the neighbor tile's rows; clamp last block)
    const int xr = (b0 + col < B_ALL) ? (b0 + col) : (B_ALL - 1);
    const float* xrow = x + (size_t)xr * (T_LEN * 32) + k0;

    // ---- prologue: xacc for t=0; prefetch x(1), x(2)
    float4v xacc;
    {
        short8 ax_hi, ax_lo;
        conv8(*(const float4v*)(xrow), *(const float4v*)(xrow + 4), &ax_hi, &ax_lo);
        float4v a = bias4;
        a = __builtin_amdgcn_mfma_f32_16x16x32_bf16(wih_hi, ax_hi, a, 0, 0, 0);
        a = __builtin_amdgcn_mfma_f32_16x16x32_bf16(wih_hi, ax_lo, a, 0, 0, 0);
        a = __builtin_amdgcn_mfma_f32_16x16x32_bf16(wih_lo, ax_hi, a, 0, 0, 0);
        xacc = a;
    }
    float4v xc_a = *(const float4v*)(xrow + 1 * 32);
    float4v xc_b = *(const float4v*)(xrow + 1 * 32 + 4);
    float4v xn_a = *(const float4v*)(xrow + 2 * 32);
    float4v xn_b = *(const float4v*)(xrow + 2 * 32 + 4);

    for (int t = 0; t < T_LEN; ++t) {
        // ---- h-projection (critical path): 3 chained MFMAs, A=W', B=H^T
        float4v acc = xacc;
        acc = __builtin_amdgcn_mfma_f32_16x16x32_bf16(whh_hi, ah_hi, acc, 0, 0, 0);
        acc = __builtin_amdgcn_mfma_f32_16x16x32_bf16(whh_hi, ah_lo, acc, 0, 0, 0);
        acc = __builtin_amdgcn_mfma_f32_16x16x32_bf16(whh_lo, ah_hi, acc, 0, 0, 0);

        // ---- lane-local LSTM cell update for (row=col, element=e)
        {
            float gi = sigf(acc[0]);
            float gf = sigf(acc[1]);
            float gg = tanh_fast(acc[2]);
            float go = sigf(acc[3]);
            float cn = gf * c + gi * gg;
            c = cn;
            float hv = go * tanh_fast(cn);
            short h_, l_;
            split_bf(hv, &h_, &l_);
            lds_hi[t & 1][col][e] = h_;
            lds_lo[t & 1][col][e] = l_;
        }

        // ---- x-projection for t+1 (off critical path, fills barrier shadow)
        if (t + 1 < T_LEN) {
            short8 ax_hi, ax_lo;
            conv8(xc_a, xc_b, &ax_hi, &ax_lo);
            float4v a = bias4;
            a = __builtin_amdgcn_mfma_f32_16x16x32_bf16(wih_hi, ax_hi, a, 0, 0, 0);
            a = __builtin_amdgcn_mfma_f32_16x16x32_bf16(wih_hi, ax_lo, a, 0, 0, 0);
            a = __builtin_amdgcn_mfma_f32_16x16x32_bf16(wih_lo, ax_hi, a, 0, 0, 0);
            xacc = a;
            // rotate prefetch pipeline: xc <- xn, issue load of x(t+3)
            xc_a = xn_a; xc_b = xn_b;
            const int tn = (t + 3 < T_LEN) ? (t + 3) : (T_LEN - 1);
            xn_a = *(const float4v*)(xrow + (size_t)tn * 32);
            xn_b = *(const float4v*)(xrow + (size_t)tn * 32 + 4);
        }

        __syncthreads();  // h visible (single barrier; double buffer handles WAR)

        // B-fragment for next step: H[b=col][k0..k0+7]
        ah_hi = *(const short8*)&lds_hi[t & 1][col][k0];
        ah_lo = *(const short8*)&lds_lo[t & 1][col][k0];
    }

    // ---- epilogue: logits = h_last @ W_fc^T + b_fc ; final h in buffer 1
    if (tid < ROWS) {
        float s = b_fc[0];
        #pragma unroll
        for (int cc = 0; cc < 32; ++cc) {
            float hv = bf2f(lds_hi[1][tid][cc]) + bf2f(lds_lo[1][tid][cc]);
            s += hv * W_fc[cc];
        }
        out[b0 + tid] = s;
    }
}

extern "C" void kernel_launch(void* const* d_in, const int* in_sizes, int n_in,
                              void* d_out, int out_size, void* d_ws, size_t ws_size,
                              hipStream_t stream) {
    const float* x    = (const float*)d_in[0];
    const float* W_ih = (const float*)d_in[1];
    const float* W_hh = (const float*)d_in[2];
    const float* b_ih = (const float*)d_in[3];
    const float* b_hh = (const float*)d_in[4];
    const float* W_fc = (const float*)d_in[5];
    const float* b_fc = (const float*)d_in[6];
    float* out = (float*)d_out;

    lstm_fused_kernel<<<dim3(NBLK), dim3(512), 0, stream>>>(
        x, W_ih, W_hh, b_ih, b_hh, W_fc, b_fc, out);
}

// Round 6
// 262.087 us; speedup vs baseline: 1.8144x; 1.8144x over previous
//
#include <hip/hip_runtime.h>
#include <stdint.h>

// PressureLSTM: B=4096, T=512, F=32, H=32, gates=128 (i,f,g,o).
// Swapped-MFMA, permuted gate index pg = e*4 + gtype (round-5 verified):
//   mfma_f32_16x16x32_bf16(A=W', B=X^T/H^T); lane's 4 acc regs = i,f,g,o of
//   (element e=4*wv+q, batch row col) -> lane-local cell update.
// NEW in r6:
//  - x staged through LDS as bf16 hi/lo fragments: 256 threads load ONE
//    coalesced dword + ONE split each (was: every lane conv8 = 8x duplicated).
//  - only 8 real rows staged; B-cols 8..15 read row col&7 (no fake fetch).
//  - weights/biases pre-scaled by -log2e (i,f,o) / 2*log2e (g): activations
//    are rcp(1+exp2(acc)) directly.
//  - two parallel MFMA chains (x & h) + vector add; t-loop unrolled x2 with
//    static buffer parity. One barrier per step.
// bf16x3 split (Whi*vhi + Whi*vlo + Wlo*vhi) ~ fp32 gate precision.

typedef __attribute__((ext_vector_type(8))) short short8;
typedef __attribute__((ext_vector_type(4))) float float4v;

#define T_LEN 512
#define B_ALL 4096
#define ROWS 8
#define NBLK (B_ALL / ROWS)   // 512 blocks -> 2 independent blocks/CU
#define P 40                  // shorts per LDS row (80 B)

static __device__ __forceinline__ void split_bf(float v, short* hi, short* lo) {
    // hi = truncated-bf16(v) (exact masked f32), lo = trunc-bf16(v - hi).
    uint32_t u = __float_as_uint(v);
    uint32_t uh = u & 0xFFFF0000u;
    float lof = v - __uint_as_float(uh);
    *hi = (short)(uh >> 16);
    *lo = (short)(__float_as_uint(lof) >> 16);
}
static __device__ __forceinline__ float bf2f(short s) {
    return __uint_as_float(((uint32_t)(uint16_t)s) << 16);
}
// gates pre-scaled at weight load: sigmoid(z) with acc = -z*log2e:
static __device__ __forceinline__ float sig_pre(float a) {
    return __builtin_amdgcn_rcpf(1.0f + __builtin_amdgcn_exp2f(a));
}
// tanh(z) with acc = 2*log2e*z:
static __device__ __forceinline__ float tanh_pre(float a) {
    return 1.0f - 2.0f * __builtin_amdgcn_rcpf(1.0f + __builtin_amdgcn_exp2f(a));
}

__global__ __launch_bounds__(512, 4) void lstm_fused_kernel(
    const float* __restrict__ x,     // [B, T, 32]
    const float* __restrict__ W_ih,  // [128, 32]
    const float* __restrict__ W_hh,  // [128, 32]
    const float* __restrict__ b_ih,  // [128]
    const float* __restrict__ b_hh,  // [128]
    const float* __restrict__ W_fc,  // [1, 32]
    const float* __restrict__ b_fc,  // [1]
    float* __restrict__ out)         // [B]
{
    const int tid  = threadIdx.x;    // 0..511
    const int wv   = tid >> 6;       // wave 0..7
    const int lane = tid & 63;
    const int col  = lane & 15;      // MFMA batch col (8..15 duplicate 0..7)
    const int q    = lane >> 4;      // 0..3
    const int k0   = q * 8;
    const int b0   = blockIdx.x * ROWS;
    const int rrow = col & 7;        // LDS row for B-fragment reads
    const int e    = 4 * wv + q;     // this lane's h element (0..31)

    __shared__ __align__(16) short hs_hi[2][ROWS][P], hs_lo[2][ROWS][P];
    __shared__ __align__(16) short xs_hi[2][ROWS][P], xs_lo[2][ROWS][P];

    // ---- A-fragment weights, pre-scaled per gate type (round-5 mapping):
    // lane holds W'[pg=16wv+col][k0..k0+7]; pg=e'*4+gt, e'=4wv+(col>>2), gt=col&3
    short8 wih_hi, wih_lo, whh_hi, whh_lo;
    {
        const int gt   = col & 3;
        const int gmem = gt * 32 + (4 * wv + (col >> 2));
        const float gs = (gt == 2) ? 2.88539008f : -1.44269504f;
        const float* wr = W_ih + gmem * 32 + k0;
        const float* hr = W_hh + gmem * 32 + k0;
        #pragma unroll
        for (int i = 0; i < 8; ++i) {
            short h_, l_;
            split_bf(wr[i] * gs, &h_, &l_);
            wih_hi[i] = h_; wih_lo[i] = l_;
            split_bf(hr[i] * gs, &h_, &l_);
            whh_hi[i] = h_; whh_lo[i] = l_;
        }
    }
    // bias for acc reg r: gate type r of element e, same pre-scale
    float4v bias4;
    #pragma unroll
    for (int r = 0; r < 4; ++r) {
        const float gs = (r == 2) ? 2.88539008f : -1.44269504f;
        bias4[r] = (b_ih[r * 32 + e] + b_hh[r * 32 + e]) * gs;
    }

    float c = 0.f;

    // ---- x staging role: 256 threads cover 8 rows x 32 k, one dword each
    const bool stager = (tid < 256);
    const int sr = (tid >> 5) & 7;   // staged row 0..7
    const int sk = tid & 31;         // k element
    const float* xsrc = x + ((size_t)(b0 + sr) * T_LEN) * 32 + sk;

    float xA = 0.f, xB = 0.f;        // x(t+1) [converting], x(t+2) [in flight]
    if (stager) {
        short h_, l_;
        split_bf(xsrc[0], &h_, &l_);         // x(0) -> xs[0]
        xs_hi[0][sr][sk] = h_;
        xs_lo[0][sr][sk] = l_;
        xA = xsrc[32];                        // x(1)
        xB = xsrc[64];                        // x(2)
        hs_hi[0][sr][sk] = 0;                 // h(-1) = 0 (shorts 0..31 read)
        hs_lo[0][sr][sk] = 0;
    }
    __syncthreads();

    // step t (parity PPAR=t&1): reads xs/hs[PPAR], writes xs/hs[PPAR^1];
    // stager converts XREG=x(t+1) and reloads XREG=x(t+3) (2-step slack).
    #define STEP(PPAR, XREG, TT)                                                \
    {                                                                           \
        const short8 ax_hi = *(const short8*)&xs_hi[PPAR][rrow][k0];            \
        const short8 ax_lo = *(const short8*)&xs_lo[PPAR][rrow][k0];            \
        const short8 ah_hi = *(const short8*)&hs_hi[PPAR][rrow][k0];            \
        const short8 ah_lo = *(const short8*)&hs_lo[PPAR][rrow][k0];            \
        float4v a1 = bias4;                                                     \
        float4v a2 = {0.f, 0.f, 0.f, 0.f};                                      \
        a1 = __builtin_amdgcn_mfma_f32_16x16x32_bf16(wih_hi, ax_hi, a1, 0,0,0); \
        a2 = __builtin_amdgcn_mfma_f32_16x16x32_bf16(whh_hi, ah_hi, a2, 0,0,0); \
        a1 = __builtin_amdgcn_mfma_f32_16x16x32_bf16(wih_hi, ax_lo, a1, 0,0,0); \
        a2 = __builtin_amdgcn_mfma_f32_16x16x32_bf16(whh_hi, ah_lo, a2, 0,0,0); \
        a1 = __builtin_amdgcn_mfma_f32_16x16x32_bf16(wih_lo, ax_hi, a1, 0,0,0); \
        a2 = __builtin_amdgcn_mfma_f32_16x16x32_bf16(whh_lo, ah_hi, a2, 0,0,0); \
        if (stager) {   /* fills MFMA shadow */                                 \
            short h_, l_;                                                       \
            split_bf(XREG, &h_, &l_);                                           \
            xs_hi[PPAR ^ 1][sr][sk] = h_;                                       \
            xs_lo[PPAR ^ 1][sr][sk] = l_;                                       \
            int tn = (TT) + 3; if (tn >= T_LEN) tn = T_LEN - 1;                 \
            XREG = xsrc[(size_t)tn * 32];                                       \
        }                                                                       \
        const float4v g = a1 + a2;                                              \
        const float gi = sig_pre(g[0]);                                         \
        const float gf = sig_pre(g[1]);                                         \
        const float gg = tanh_pre(g[2]);                                        \
        const float go = sig_pre(g[3]);                                         \
        c = gf * c + gi * gg;                                                   \
        const float hv = go * tanh_pre(c * 2.88539008f);                        \
        if (col < 8) {                                                          \
            short h_, l_;                                                       \
            split_bf(hv, &h_, &l_);                                             \
            hs_hi[PPAR ^ 1][col][e] = h_;                                       \
            hs_lo[PPAR ^ 1][col][e] = l_;                                       \
        }                                                                       \
        __syncthreads();                                                        \
    }

    for (int t = 0; t < T_LEN; t += 2) {
        STEP(0, xA, t)
        STEP(1, xB, t + 1)
    }
    #undef STEP

    // ---- epilogue: h(511) was written to buffer 0 (step 511, parity 1 -> ^1)
    if (tid < ROWS) {
        float s = b_fc[0];
        #pragma unroll
        for (int cc = 0; cc < 32; ++cc) {
            float hvv = bf2f(hs_hi[0][tid][cc]) + bf2f(hs_lo[0][tid][cc]);
            s += hvv * W_fc[cc];
        }
        out[b0 + tid] = s;
    }
}

extern "C" void kernel_launch(void* const* d_in, const int* in_sizes, int n_in,
                              void* d_out, int out_size, void* d_ws, size_t ws_size,
                              hipStream_t stream) {
    const float* x    = (const float*)d_in[0];
    const float* W_ih = (const float*)d_in[1];
    const float* W_hh = (const float*)d_in[2];
    const float* b_ih = (const float*)d_in[3];
    const float* b_hh = (const float*)d_in[4];
    const float* W_fc = (const float*)d_in[5];
    const float* b_fc = (const float*)d_in[6];
    float* out = (float*)d_out;

    lstm_fused_kernel<<<dim3(NBLK), dim3(512), 0, stream>>>(
        x, W_ih, W_hh, b_ih, b_hh, W_fc, b_fc, out);
}

// Round 7
// 172.219 us; speedup vs baseline: 2.7612x; 1.5218x over previous
//
#include <hip/hip_runtime.h>
#include <stdint.h>

// PressureLSTM: B=4096, T=512, F=32, H=32, gates=128 (i,f,g,o).
// Swapped-MFMA, permuted gate index pg = e*4 + gtype (verified r5/r6):
//   mfma_f32_16x16x32_bf16(A=W', B=X^T/H^T); lane's 4 acc regs = i,f,g,o of
//   (element e=4*wv+q, batch row col) -> lane-local cell update.
// r7: ROWS=16 -> ALL 16 MFMA columns real (no duplicate lanes): per-cell
//   issue work halves vs r6. 256 blocks x 512 threads, 1 block/CU.
//   - balanced stager: every thread stages one x dword (sr=tid>>5, sk=tid&31)
//   - fused-rcp activations (8 trans/cell instead of 10), c clamped to +-16
//     so the fused o*tanh(c) form cannot produce inf/inf
//   - two parallel MFMA chains (x-chain, h-chain) + one vector add
// bf16x3 split (Whi*vhi + Whi*vlo + Wlo*vhi) ~ fp32 gate precision.

typedef __attribute__((ext_vector_type(8))) short short8;
typedef __attribute__((ext_vector_type(4))) float float4v;

#define T_LEN 512
#define B_ALL 4096
#define ROWS 16
#define NBLK (B_ALL / ROWS)   // 256 blocks -> 1 block/CU
#define P 40                  // shorts per LDS row (80 B)

static __device__ __forceinline__ void split_bf(float v, short* hi, short* lo) {
    // hi = truncated-bf16(v) (exact masked f32), lo = trunc-bf16(v - hi).
    uint32_t u = __float_as_uint(v);
    uint32_t uh = u & 0xFFFF0000u;
    float lof = v - __uint_as_float(uh);
    *hi = (short)(uh >> 16);
    *lo = (short)(__float_as_uint(lof) >> 16);
}
static __device__ __forceinline__ float bf2f(short s) {
    return __uint_as_float(((uint32_t)(uint16_t)s) << 16);
}

__global__ __launch_bounds__(512, 2) void lstm_fused_kernel(
    const float* __restrict__ x,     // [B, T, 32]
    const float* __restrict__ W_ih,  // [128, 32]
    const float* __restrict__ W_hh,  // [128, 32]
    const float* __restrict__ b_ih,  // [128]
    const float* __restrict__ b_hh,  // [128]
    const float* __restrict__ W_fc,  // [1, 32]
    const float* __restrict__ b_fc,  // [1]
    float* __restrict__ out)         // [B]
{
    const int tid  = threadIdx.x;    // 0..511
    const int wv   = tid >> 6;       // wave 0..7
    const int lane = tid & 63;
    const int col  = lane & 15;      // batch row within tile (all real)
    const int q    = lane >> 4;      // 0..3
    const int k0   = q * 8;
    const int b0   = blockIdx.x * ROWS;
    const int e    = 4 * wv + q;     // this lane's h element (0..31)

    __shared__ __align__(16) short hs_hi[2][ROWS][P], hs_lo[2][ROWS][P];
    __shared__ __align__(16) short xs_hi[2][ROWS][P], xs_lo[2][ROWS][P];

    // ---- A-fragment weights, pre-scaled per gate type (verified mapping):
    // lane holds W'[pg=16wv+col][k0..k0+7]; pg=e'*4+gt, e'=4wv+(col>>2), gt=col&3
    // scale: i,f,o by -log2e (sigmoid via rcp(1+exp2)); g by +2*log2e (tanh).
    short8 wih_hi, wih_lo, whh_hi, whh_lo;
    {
        const int gt   = col & 3;
        const int gmem = gt * 32 + (4 * wv + (col >> 2));
        const float gs = (gt == 2) ? 2.88539008f : -1.44269504f;
        const float* wr = W_ih + gmem * 32 + k0;
        const float* hr = W_hh + gmem * 32 + k0;
        #pragma unroll
        for (int i = 0; i < 8; ++i) {
            short h_, l_;
            split_bf(wr[i] * gs, &h_, &l_);
            wih_hi[i] = h_; wih_lo[i] = l_;
            split_bf(hr[i] * gs, &h_, &l_);
            whh_hi[i] = h_; whh_lo[i] = l_;
        }
    }
    // bias for acc reg r: gate type r of element e, same pre-scale
    float4v bias4;
    #pragma unroll
    for (int r = 0; r < 4; ++r) {
        const float gs = (r == 2) ? 2.88539008f : -1.44269504f;
        bias4[r] = (b_ih[r * 32 + e] + b_hh[r * 32 + e]) * gs;
    }

    float c = 0.f;

    // ---- x staging: all 512 threads cover 16 rows x 32 k, one dword each
    const int sr = tid >> 5;         // staged row 0..15
    const int sk = tid & 31;         // k element
    const float* xsrc = x + ((size_t)(b0 + sr) * T_LEN) * 32 + sk;

    float xA, xB;                    // x(t+1) [to convert], x(t+2) [in flight]
    {
        short h_, l_;
        split_bf(xsrc[0], &h_, &l_);          // x(0) -> xs[0]
        xs_hi[0][sr][sk] = h_;
        xs_lo[0][sr][sk] = l_;
        xA = xsrc[32];                         // x(1)
        xB = xsrc[64];                         // x(2)
        hs_hi[0][sr][sk] = 0;                  // h(-1) = 0
        hs_lo[0][sr][sk] = 0;
    }
    __syncthreads();

    // step t (parity PPAR=t&1): reads xs/hs[PPAR], writes xs/hs[PPAR^1];
    // every thread converts XREG=x(t+1) and reloads XREG=x(t+3) (2-step slack).
    #define STEP(PPAR, XREG, TT)                                                \
    {                                                                           \
        const short8 ax_hi = *(const short8*)&xs_hi[PPAR][col][k0];             \
        const short8 ax_lo = *(const short8*)&xs_lo[PPAR][col][k0];             \
        const short8 ah_hi = *(const short8*)&hs_hi[PPAR][col][k0];             \
        const short8 ah_lo = *(const short8*)&hs_lo[PPAR][col][k0];             \
        float4v a1 = bias4;                                                     \
        float4v a2 = {0.f, 0.f, 0.f, 0.f};                                      \
        a1 = __builtin_amdgcn_mfma_f32_16x16x32_bf16(wih_hi, ax_hi, a1, 0,0,0); \
        a2 = __builtin_amdgcn_mfma_f32_16x16x32_bf16(whh_hi, ah_hi, a2, 0,0,0); \
        a1 = __builtin_amdgcn_mfma_f32_16x16x32_bf16(wih_hi, ax_lo, a1, 0,0,0); \
        a2 = __builtin_amdgcn_mfma_f32_16x16x32_bf16(whh_hi, ah_lo, a2, 0,0,0); \
        a1 = __builtin_amdgcn_mfma_f32_16x16x32_bf16(wih_lo, ax_hi, a1, 0,0,0); \
        a2 = __builtin_amdgcn_mfma_f32_16x16x32_bf16(whh_lo, ah_hi, a2, 0,0,0); \
        {   /* stage x(t+1) -> buffer PPAR^1 (fills MFMA shadow) */             \
            short h_, l_;                                                       \
            split_bf(XREG, &h_, &l_);                                           \
            xs_hi[PPAR ^ 1][sr][sk] = h_;                                       \
            xs_lo[PPAR ^ 1][sr][sk] = l_;                                       \
            int tn = (TT) + 3; if (tn >= T_LEN) tn = T_LEN - 1;                 \
            XREG = xsrc[(size_t)tn * 32];                                       \
        }                                                                       \
        const float4v g = a1 + a2;                                              \
        /* fused activations: acc = pre-scaled gate pre-acts               */   \
        /* gi*gg = (Bg-1)*rcp((1+Ai)(1+Bg)); go*tanh(cc) = (C2-1)*rcp(..) */    \
        const float Ai = __builtin_amdgcn_exp2f(g[0]);                          \
        const float Af = __builtin_amdgcn_exp2f(g[1]);                          \
        const float Bg = __builtin_amdgcn_exp2f(g[2]);                          \
        const float Ao = __builtin_amdgcn_exp2f(g[3]);                          \
        const float gf = __builtin_amdgcn_rcpf(1.0f + Af);                      \
        const float r1 = __builtin_amdgcn_rcpf((1.0f + Ai) * (1.0f + Bg));      \
        c = gf * c + (Bg - 1.0f) * r1;                                          \
        const float cc = fminf(fmaxf(c, -16.0f), 16.0f);                        \
        const float C2 = __builtin_amdgcn_exp2f(cc * 2.88539008f);              \
        const float r3 = __builtin_amdgcn_rcpf((1.0f + Ao) * (1.0f + C2));      \
        const float hv = (C2 - 1.0f) * r3;                                      \
        {                                                                       \
            short h_, l_;                                                       \
            split_bf(hv, &h_, &l_);                                             \
            hs_hi[PPAR ^ 1][col][e] = h_;                                       \
            hs_lo[PPAR ^ 1][col][e] = l_;                                       \
        }                                                                       \
        __syncthreads();                                                        \
    }

    for (int t = 0; t < T_LEN; t += 2) {
        STEP(0, xA, t)
        STEP(1, xB, t + 1)
    }
    #undef STEP

    // ---- epilogue: h(511) was written to buffer 0 (step 511 has parity 1)
    if (tid < ROWS) {
        float s = b_fc[0];
        #pragma unroll
        for (int cc2 = 0; cc2 < 32; ++cc2) {
            float hvv = bf2f(hs_hi[0][tid][cc2]) + bf2f(hs_lo[0][tid][cc2]);
            s += hvv * W_fc[cc2];
        }
        out[b0 + tid] = s;
    }
}

extern "C" void kernel_launch(void* const* d_in, const int* in_sizes, int n_in,
                              void* d_out, int out_size, void* d_ws, size_t ws_size,
                              hipStream_t stream) {
    const float* x    = (const float*)d_in[0];
    const float* W_ih = (const float*)d_in[1];
    const float* W_hh = (const float*)d_in[2];
    const float* b_ih = (const float*)d_in[3];
    const float* b_hh = (const float*)d_in[4];
    const float* W_fc = (const float*)d_in[5];
    const float* b_fc = (const float*)d_in[6];
    float* out = (float*)d_out;

    lstm_fused_kernel<<<dim3(NBLK), dim3(512), 0, stream>>>(
        x, W_ih, W_hh, b_ih, b_hh, W_fc, b_fc, out);
}